// Round 3
// baseline (468.180 us; speedup 1.0000x reference)
//
#include <hip/hip_runtime.h>
#include <hip/hip_bf16.h>

typedef __hip_bfloat16 bf16;

#define N_NODES 50000
#define N_EDGES 800000
#define DIM 128

__device__ __forceinline__ float b2f(bf16 v) { return __bfloat162float(v); }

// Generic scalar float load: isb=1 -> buffer is bf16, else fp32.
// Explicit branch (not ternary) so the compiler cannot if-convert into a
// speculative OOB load on the wrong-dtype address.
__device__ __forceinline__ float loadf(const void* p, int i, int isb) {
    if (isb) return b2f(((const bf16*)p)[i]);
    return ((const float*)p)[i];
}

// ---------------- runtime dtype detection ----------------
// flags[0]: 1 if float tensors are bf16, 0 if fp32.
//   For bf16 data, word bits[14:7] = exponent of the low-half bf16 of ~N(0,1)
//   values -> concentrated in [107,130]. For fp32 data these are low mantissa
//   bits -> uniform. Count hits in [100,141] over 128 words.
// flags[1]: 1 if edge_index is int64-stored (odd int32 words all zero).
__global__ void detect_kernel(const unsigned* __restrict__ xw, const int* __restrict__ ei,
                              int* __restrict__ flags) {
    if (threadIdx.x == 0) {
        int hits = 0;
        for (int k = 0; k < 128; k++) {
            unsigned e = (xw[k] >> 7) & 0xFFu;
            if (e >= 100u && e <= 141u) hits++;
        }
        flags[0] = (hits >= 64) ? 1 : 0;
        int acc = 0;
        for (int k = 0; k < 64; k++) acc |= ei[2 * k + 1];
        flags[1] = (acc == 0) ? 1 : 0;
    }
}

// ---------------- CSR build ----------------

__global__ void zero_kernel(int* __restrict__ p, int n) {
    int i = blockIdx.x * blockDim.x + threadIdx.x;
    if (i < n) p[i] = 0;
}

__global__ void hist_kernel(const int* __restrict__ ei, const int* __restrict__ flags,
                            int* __restrict__ cnt) {
    int e = blockIdx.x * blockDim.x + threadIdx.x;
    if (e < N_EDGES) {
        int j = N_EDGES + e;
        if (flags[1]) j *= 2;          // int64 storage: value lives in even word
        atomicAdd(&cnt[ei[j]], 1);
    }
}

// block = 256 threads, 1024 counts per block -> block sums
__global__ void scan_part(const int* __restrict__ cnt, int* __restrict__ bsums) {
    __shared__ int s[256];
    int t = threadIdx.x;
    int base = blockIdx.x * 1024;
    int v = 0;
    #pragma unroll
    for (int j = 0; j < 4; j++) {
        int i = base + j * 256 + t;
        if (i < N_NODES) v += cnt[i];
    }
    s[t] = v;
    __syncthreads();
    for (int off = 128; off > 0; off >>= 1) {
        if (t < off) s[t] += s[t + off];
        __syncthreads();
    }
    if (t == 0) bsums[blockIdx.x] = s[0];
}

__global__ void scan_tops(const int* __restrict__ bsums, int* __restrict__ boffs,
                          int* __restrict__ offsets, int nb) {
    if (threadIdx.x == 0) {
        int run = 0;
        for (int i = 0; i < nb; i++) { boffs[i] = run; run += bsums[i]; }
        offsets[N_NODES] = run;  // == N_EDGES
    }
}

__global__ void scan_down(const int* __restrict__ cnt, const int* __restrict__ boffs,
                          int* __restrict__ offsets, int* __restrict__ cursor) {
    __shared__ int s[256];
    int t = threadIdx.x;
    int base = blockIdx.x * 1024 + t * 4;
    int c0 = 0, c1 = 0, c2 = 0, c3 = 0;
    if (base     < N_NODES) c0 = cnt[base];
    if (base + 1 < N_NODES) c1 = cnt[base + 1];
    if (base + 2 < N_NODES) c2 = cnt[base + 2];
    if (base + 3 < N_NODES) c3 = cnt[base + 3];
    int ts = c0 + c1 + c2 + c3;
    s[t] = ts;
    __syncthreads();
    for (int off = 1; off < 256; off <<= 1) {
        int v = (t >= off) ? s[t - off] : 0;
        __syncthreads();
        s[t] += v;
        __syncthreads();
    }
    int p = boffs[blockIdx.x] + s[t] - ts;  // exclusive prefix
    if (base     < N_NODES) { offsets[base]     = p; cursor[base]     = p; p += c0; }
    if (base + 1 < N_NODES) { offsets[base + 1] = p; cursor[base + 1] = p; p += c1; }
    if (base + 2 < N_NODES) { offsets[base + 2] = p; cursor[base + 2] = p; p += c2; }
    if (base + 3 < N_NODES) { offsets[base + 3] = p; cursor[base + 3] = p; p += c3; }
}

__global__ void fill_kernel(const int* __restrict__ ei, const int* __restrict__ flags,
                            int* __restrict__ cursor, int* __restrict__ nbrs) {
    int e = blockIdx.x * blockDim.x + threadIdx.x;
    if (e < N_EDGES) {
        int jd = N_EDGES + e, js = e;
        if (flags[1]) { jd *= 2; js *= 2; }
        int d = ei[jd];
        int p = atomicAdd(&cursor[d], 1);
        nbrs[p] = ei[js];
    }
}

// ---------------- aggregation: h = (1+eps)*x + sum_{j in N(i)} x_j ----------------
// 256 threads = 2 nodes x 128 features
__global__ void agg_kernel(const void* __restrict__ x, const int* __restrict__ offsets,
                           const int* __restrict__ nbrs, const void* __restrict__ epsp,
                           const int* __restrict__ flags, float* __restrict__ h) {
    int isb = flags[0];
    int node = blockIdx.x * 2 + (threadIdx.x >> 7);
    int f = threadIdx.x & 127;
    if (node >= N_NODES) return;
    float ep = loadf(epsp, 0, isb);
    int s = offsets[node], e = offsets[node + 1];
    float acc;
    if (isb) {
        const bf16* xb = (const bf16*)x;
        acc = (1.0f + ep) * b2f(xb[node * DIM + f]);
        for (int i = s; i < e; i++) acc += b2f(xb[nbrs[i] * DIM + f]);
    } else {
        const float* xf = (const float*)x;
        acc = (1.0f + ep) * xf[node * DIM + f];
        for (int i = s; i < e; i++) acc += xf[nbrs[i] * DIM + f];
    }
    h[node * DIM + f] = acc;
}

// ---------------- W transpose to fp32: WT[k*128+o] = W[o*128+k] ----------------
__global__ void transpose_kernel(const void* __restrict__ W1, const void* __restrict__ W2,
                                 const int* __restrict__ flags,
                                 float* __restrict__ WT1, float* __restrict__ WT2) {
    int isb = flags[0];
    int i = blockIdx.x * blockDim.x + threadIdx.x;  // 0..32767
    const void* W = (i < 16384) ? W1 : W2;
    float* WT = (i < 16384) ? WT1 : WT2;
    int j = i & 16383;
    int o = j >> 7, k = j & 127;
    WT[k * DIM + o] = loadf(W, j, isb);
}

// ---------------- GEMM: Y[r][o] = sum_k T(H[r][k]) * WT[k][o] + bias[o] ----------------
// T = identity, or relu(x*scale[k]+shift[k]) when scale != nullptr (fused BN1+ReLU).
// block 256 threads, 32 rows x 128 cols per block; thread: 4 rows x 4 cols.
// NOTE: Hin/Yout may alias (in-place GEMM2): each block reads only its own output
// rows, and all reads happen before any write -> safe. No __restrict__ on these.
__launch_bounds__(256)
__global__ void gemm_kernel(const float* Hin, const float* __restrict__ WT,
                            const void* __restrict__ bias, const int* __restrict__ flags,
                            const float* __restrict__ scale, const float* __restrict__ shift,
                            float* Yout) {
    __shared__ float sW[32 * 128];   // [k][o] chunk
    __shared__ float sH[32 * 36];    // [k][row], padded row stride 36 (16B-aligned)
    __shared__ float sScale[128], sShift[128];

    int isb = flags[0];
    int t = threadIdx.x;
    int tx = t & 31;          // col group: cols tx*4..tx*4+3
    int ty = t >> 5;          // row group: rows ty*4..ty*4+3
    int r0 = blockIdx.x * 32;
    int c = tx * 4;
    bool useBN = (scale != nullptr);
    if (useBN && t < 128) { sScale[t] = scale[t]; sShift[t] = shift[t]; }

    float4 acc[4];
    #pragma unroll
    for (int rr = 0; rr < 4; rr++) acc[rr] = make_float4(0.f, 0.f, 0.f, 0.f);
    __syncthreads();

    for (int kc = 0; kc < 128; kc += 32) {
        // stage H tile transposed: sH[k][row]
        {
            int row = t >> 3;           // 0..31
            int k4 = (t & 7) * 4;       // 0,4,..28
            int grow = r0 + row;
            float4 hv = make_float4(0.f, 0.f, 0.f, 0.f);
            if (grow < N_NODES) hv = *(const float4*)&Hin[grow * DIM + kc + k4];
            float v[4] = {hv.x, hv.y, hv.z, hv.w};
            #pragma unroll
            for (int j = 0; j < 4; j++) {
                float val = v[j];
                if (useBN) {
                    int kk = kc + k4 + j;
                    val = fmaxf(val * sScale[kk] + sShift[kk], 0.0f);
                }
                sH[(k4 + j) * 36 + row] = val;
            }
        }
        // stage W chunk: 32k x 128o, straight copy (layouts match)
        #pragma unroll
        for (int it = 0; it < 4; it++) {
            int w4 = (it * 256 + t) * 4;
            *(float4*)&sW[w4] = *(const float4*)&WT[kc * DIM + w4];
        }
        __syncthreads();

        #pragma unroll
        for (int kk = 0; kk < 32; kk++) {
            float4 w = *(const float4*)&sW[kk * 128 + c];
            float4 a = *(const float4*)&sH[kk * 36 + ty * 4];
            acc[0].x = fmaf(a.x, w.x, acc[0].x); acc[0].y = fmaf(a.x, w.y, acc[0].y);
            acc[0].z = fmaf(a.x, w.z, acc[0].z); acc[0].w = fmaf(a.x, w.w, acc[0].w);
            acc[1].x = fmaf(a.y, w.x, acc[1].x); acc[1].y = fmaf(a.y, w.y, acc[1].y);
            acc[1].z = fmaf(a.y, w.z, acc[1].z); acc[1].w = fmaf(a.y, w.w, acc[1].w);
            acc[2].x = fmaf(a.z, w.x, acc[2].x); acc[2].y = fmaf(a.z, w.y, acc[2].y);
            acc[2].z = fmaf(a.z, w.z, acc[2].z); acc[2].w = fmaf(a.z, w.w, acc[2].w);
            acc[3].x = fmaf(a.w, w.x, acc[3].x); acc[3].y = fmaf(a.w, w.y, acc[3].y);
            acc[3].z = fmaf(a.w, w.z, acc[3].z); acc[3].w = fmaf(a.w, w.w, acc[3].w);
        }
        __syncthreads();
    }

    float4 bb;
    bb.x = loadf(bias, c, isb);     bb.y = loadf(bias, c + 1, isb);
    bb.z = loadf(bias, c + 2, isb); bb.w = loadf(bias, c + 3, isb);
    #pragma unroll
    for (int rr = 0; rr < 4; rr++) {
        int grow = r0 + ty * 4 + rr;
        if (grow < N_NODES) {
            float4 o;
            o.x = acc[rr].x + bb.x; o.y = acc[rr].y + bb.y;
            o.z = acc[rr].z + bb.z; o.w = acc[rr].w + bb.w;
            *(float4*)&Yout[grow * DIM + c] = o;
        }
    }
}

// ---------------- BN stats: per-column sum / sumsq ----------------
__global__ void stats_kernel(const float* __restrict__ Y, float* __restrict__ sum,
                             float* __restrict__ sumsq) {
    __shared__ float ssum[256], ssq[256];
    int t = threadIdx.x;
    int c = t & 127;
    int rp = t >> 7;
    float s = 0.f, q = 0.f;
    for (int r = blockIdx.x * 2 + rp; r < N_NODES; r += gridDim.x * 2) {
        float v = Y[r * DIM + c];
        s += v; q += v * v;
    }
    ssum[t] = s; ssq[t] = q;
    __syncthreads();
    if (t < 128) {
        s = ssum[t] + ssum[t + 128];
        q = ssq[t] + ssq[t + 128];
        atomicAdd(&sum[c], s);
        atomicAdd(&sumsq[c], q);
    }
}

__global__ void finalize_kernel(const float* __restrict__ sum, const float* __restrict__ sumsq,
                                const void* __restrict__ gamma, const void* __restrict__ beta,
                                const int* __restrict__ flags,
                                float* __restrict__ scale, float* __restrict__ shift) {
    int isb = flags[0];
    int c = threadIdx.x;
    if (c < 128) {
        float m = sum[c] * (1.0f / N_NODES);
        float v = sumsq[c] * (1.0f / N_NODES) - m * m;
        v = fmaxf(v, 0.0f);
        float rs = rsqrtf(v + 1e-5f);
        float sc = loadf(gamma, c, isb) * rs;
        scale[c] = sc;
        shift[c] = loadf(beta, c, isb) - m * sc;
    }
}

// ---------------- final BN2 + ReLU + cast to output dtype ----------------
__global__ void output_kernel(const float* __restrict__ Y, const float* __restrict__ scale,
                              const float* __restrict__ shift, const int* __restrict__ flags,
                              void* __restrict__ out) {
    int isb = flags[0];
    int i = (blockIdx.x * blockDim.x + threadIdx.x) * 4;
    if (i >= N_NODES * DIM) return;
    int c = i & 127;
    float4 v = *(const float4*)&Y[i];
    float o0 = fmaxf(fmaf(v.x, scale[c],     shift[c]),     0.f);
    float o1 = fmaxf(fmaf(v.y, scale[c + 1], shift[c + 1]), 0.f);
    float o2 = fmaxf(fmaf(v.z, scale[c + 2], shift[c + 2]), 0.f);
    float o3 = fmaxf(fmaf(v.w, scale[c + 3], shift[c + 3]), 0.f);
    if (isb) {
        bf16 r[4] = {__float2bfloat16(o0), __float2bfloat16(o1),
                     __float2bfloat16(o2), __float2bfloat16(o3)};
        *(uint2*)&((bf16*)out)[i] = *(uint2*)r;
    } else {
        *(float4*)&((float*)out)[i] = make_float4(o0, o1, o2, o3);
    }
}

extern "C" void kernel_launch(void* const* d_in, const int* in_sizes, int n_in,
                              void* d_out, int out_size, void* d_ws, size_t ws_size,
                              hipStream_t stream) {
    const void* x    = d_in[0];
    const int*  eraw = (const int*)d_in[1];
    // d_in[2] = batch (unused)
    const void* eps  = d_in[3];
    const void* W1   = d_in[4];
    const void* b1   = d_in[5];
    const void* g1   = d_in[6];
    const void* be1  = d_in[7];
    const void* W2   = d_in[8];
    const void* b2   = d_in[9];
    const void* g2   = d_in[10];
    const void* be2  = d_in[11];

    char* ws = (char*)d_ws;
    size_t off = 0;
    float* h = (float*)(ws + off);      off += (size_t)N_NODES * DIM * 4;  // 25.6 MB
    float* y = (float*)(ws + off);      off += (size_t)N_NODES * DIM * 4;  // 25.6 MB
    float* WT1 = (float*)(ws + off);    off += DIM * DIM * 4;
    float* WT2 = (float*)(ws + off);    off += DIM * DIM * 4;
    int* cnt = (int*)(ws + off);        off += (size_t)N_NODES * 4;        // zero-region start
    float* stats = (float*)(ws + off);  off += 4 * 128 * 4;                // sum1,sq1,sum2,sq2
    float* sum1 = stats, *sq1 = stats + 128, *sum2 = stats + 256, *sq2 = stats + 384;
    float* scale1 = (float*)(ws + off); off += 128 * 4;
    float* shift1 = (float*)(ws + off); off += 128 * 4;
    float* scale2 = (float*)(ws + off); off += 128 * 4;
    float* shift2 = (float*)(ws + off); off += 128 * 4;
    int* offsets = (int*)(ws + off);    off += (size_t)(N_NODES + 16) * 4;
    int* cursor = (int*)(ws + off);     off += (size_t)(N_NODES + 16) * 4;
    int* nbrs = (int*)(ws + off);       off += (size_t)N_EDGES * 4;
    int* bsums = (int*)(ws + off);      off += 64 * 4;
    int* boffs = (int*)(ws + off);      off += 64 * 4;
    int* flags = (int*)(ws + off);      off += 16 * 4;

    const int nbScan = (N_NODES + 1023) / 1024;  // 49

    detect_kernel<<<1, 64, 0, stream>>>((const unsigned*)x, eraw, flags);

    // zero cnt + stats (contiguous region)
    int zn = N_NODES + 4 * 128;
    zero_kernel<<<(zn + 255) / 256, 256, 0, stream>>>(cnt, zn);
    hist_kernel<<<(N_EDGES + 255) / 256, 256, 0, stream>>>(eraw, flags, cnt);
    scan_part<<<nbScan, 256, 0, stream>>>(cnt, bsums);
    scan_tops<<<1, 64, 0, stream>>>(bsums, boffs, offsets, nbScan);
    scan_down<<<nbScan, 256, 0, stream>>>(cnt, boffs, offsets, cursor);
    fill_kernel<<<(N_EDGES + 255) / 256, 256, 0, stream>>>(eraw, flags, cursor, nbrs);
    agg_kernel<<<(N_NODES + 1) / 2, 256, 0, stream>>>(x, offsets, nbrs, eps, flags, h);
    transpose_kernel<<<128, 256, 0, stream>>>(W1, W2, flags, WT1, WT2);

    const int gemmGrid = (N_NODES + 31) / 32;  // 1563
    gemm_kernel<<<gemmGrid, 256, 0, stream>>>(h, WT1, b1, flags, nullptr, nullptr, y);
    stats_kernel<<<512, 256, 0, stream>>>(y, sum1, sq1);
    finalize_kernel<<<1, 128, 0, stream>>>(sum1, sq1, g1, be1, flags, scale1, shift1);
    // GEMM2 with fused BN1+ReLU on input; in-place (each block reads its rows fully before writing)
    gemm_kernel<<<gemmGrid, 256, 0, stream>>>(y, WT2, b2, flags, scale1, shift1, y);
    stats_kernel<<<512, 256, 0, stream>>>(y, sum2, sq2);
    finalize_kernel<<<1, 128, 0, stream>>>(sum2, sq2, g2, be2, flags, scale2, shift2);
    output_kernel<<<(N_NODES * DIM / 4 + 255) / 256, 256, 0, stream>>>(y, scale2, shift2, flags, d_out);
}

// Round 5
// 331.038 us; speedup vs baseline: 1.4143x; 1.4143x over previous
//
#include <hip/hip_runtime.h>
#include <hip/hip_bf16.h>

typedef __hip_bfloat16 bf16;
typedef unsigned short u16;
typedef __attribute__((ext_vector_type(8))) short short8;
typedef __attribute__((ext_vector_type(4))) float floatx4;

#define N_NODES 50000
#define N_EDGES 800000
#define DIM 128

__device__ __forceinline__ u16 f2bfbits(float f) {
    bf16 h = __float2bfloat16(f);
    return *(u16*)&h;
}
__device__ __forceinline__ unsigned pack2(float a, float b) {
    return (unsigned)f2bfbits(a) | ((unsigned)f2bfbits(b) << 16);
}

// ---------------- edge_index storage detect (int64 vs int32) ----------------
__global__ void detect_kernel(const int* __restrict__ ei, int* __restrict__ flags) {
    if (threadIdx.x == 0) {
        int acc = 0;
        for (int k = 0; k < 64; k++) acc |= ei[2 * k + 1];
        flags[1] = (acc == 0) ? 1 : 0;
    }
}

// ---------------- CSR build ----------------

__global__ void zero_kernel(int* __restrict__ p, int n) {
    int i = blockIdx.x * blockDim.x + threadIdx.x;
    if (i < n) p[i] = 0;
}

__global__ void hist_kernel(const int* __restrict__ ei, const int* __restrict__ flags,
                            int* __restrict__ cnt) {
    int e = blockIdx.x * blockDim.x + threadIdx.x;
    if (e < N_EDGES) {
        int j = N_EDGES + e;
        if (flags[1]) j *= 2;
        atomicAdd(&cnt[ei[j]], 1);
    }
}

__global__ void scan_part(const int* __restrict__ cnt, int* __restrict__ bsums) {
    __shared__ int s[256];
    int t = threadIdx.x;
    int base = blockIdx.x * 1024;
    int v = 0;
    #pragma unroll
    for (int j = 0; j < 4; j++) {
        int i = base + j * 256 + t;
        if (i < N_NODES) v += cnt[i];
    }
    s[t] = v;
    __syncthreads();
    for (int off = 128; off > 0; off >>= 1) {
        if (t < off) s[t] += s[t + off];
        __syncthreads();
    }
    if (t == 0) bsums[blockIdx.x] = s[0];
}

__global__ void scan_tops(const int* __restrict__ bsums, int* __restrict__ boffs,
                          int* __restrict__ offsets, int nb) {
    if (threadIdx.x == 0) {
        int run = 0;
        for (int i = 0; i < nb; i++) { boffs[i] = run; run += bsums[i]; }
        offsets[N_NODES] = run;
    }
}

__global__ void scan_down(const int* __restrict__ cnt, const int* __restrict__ boffs,
                          int* __restrict__ offsets, int* __restrict__ cursor) {
    __shared__ int s[256];
    int t = threadIdx.x;
    int base = blockIdx.x * 1024 + t * 4;
    int c0 = 0, c1 = 0, c2 = 0, c3 = 0;
    if (base     < N_NODES) c0 = cnt[base];
    if (base + 1 < N_NODES) c1 = cnt[base + 1];
    if (base + 2 < N_NODES) c2 = cnt[base + 2];
    if (base + 3 < N_NODES) c3 = cnt[base + 3];
    int ts = c0 + c1 + c2 + c3;
    s[t] = ts;
    __syncthreads();
    for (int off = 1; off < 256; off <<= 1) {
        int v = (t >= off) ? s[t - off] : 0;
        __syncthreads();
        s[t] += v;
        __syncthreads();
    }
    int p = boffs[blockIdx.x] + s[t] - ts;
    if (base     < N_NODES) { offsets[base]     = p; cursor[base]     = p; p += c0; }
    if (base + 1 < N_NODES) { offsets[base + 1] = p; cursor[base + 1] = p; p += c1; }
    if (base + 2 < N_NODES) { offsets[base + 2] = p; cursor[base + 2] = p; p += c2; }
    if (base + 3 < N_NODES) { offsets[base + 3] = p; cursor[base + 3] = p; p += c3; }
}

__global__ void fill_kernel(const int* __restrict__ ei, const int* __restrict__ flags,
                            int* __restrict__ cursor, int* __restrict__ nbrs) {
    int e = blockIdx.x * blockDim.x + threadIdx.x;
    if (e < N_EDGES) {
        int jd = N_EDGES + e, js = e;
        if (flags[1]) { jd *= 2; js *= 2; }
        int d = ei[jd];
        int p = atomicAdd(&cursor[d], 1);
        nbrs[p] = ei[js];
    }
}

// ---------------- aggregation: h = (1+eps)*x + sum_{j in N(i)} x_j ----------------
// x fp32. wave per node; lane = float2 (64 lanes * 8 B = 512 B row).
// neighbor loop 4x unrolled -> 4 independent row loads in flight.
// h written as bf16 (packed pairs) to feed MFMA GEMM1 directly.
__global__ void agg_kernel(const float2* __restrict__ xw, const int* __restrict__ offsets,
                           const int* __restrict__ nbrs, const float* __restrict__ epsp,
                           unsigned* __restrict__ hw) {
    int lane = threadIdx.x & 63;
    int node = blockIdx.x * 4 + (threadIdx.x >> 6);  // 12500 * 4 = 50000 exactly
    float ep1 = 1.0f + epsp[0];
    float2 self = xw[node * 64 + lane];
    float ax = ep1 * self.x, ay = ep1 * self.y;
    int s = offsets[node], e = offsets[node + 1];
    int i = s;
    for (; i + 4 <= e; i += 4) {
        int n0 = nbrs[i], n1 = nbrs[i + 1], n2 = nbrs[i + 2], n3 = nbrs[i + 3];
        float2 u0 = xw[n0 * 64 + lane];
        float2 u1 = xw[n1 * 64 + lane];
        float2 u2 = xw[n2 * 64 + lane];
        float2 u3 = xw[n3 * 64 + lane];
        ax += u0.x + u1.x + u2.x + u3.x;
        ay += u0.y + u1.y + u2.y + u3.y;
    }
    for (; i < e; i++) {
        float2 u = xw[nbrs[i] * 64 + lane];
        ax += u.x; ay += u.y;
    }
    hw[node * 64 + lane] = pack2(ax, ay);
}

// ---------------- MFMA GEMM: Y[m][o] = sum_k T(A[m][k]) * W[o][k] + bias[o] ----------------
// W fp32 [O][K] row-major, converted to bf16 during LDS staging. B-fragment for
// 16x16x32: lane holds B[k=quad*8+j][n=lane&15] = W[n][k] -> contiguous 8 u16 of sW row n.
// TRANSFORM=1: A is fp32 y, apply relu(a*scale[k]+shift[k]) then cast bf16 (fused BN1+ReLU).
// Fused BN stats: wave shfl-reduce -> LDS -> one global atomic set per block.
// In-place safe (Ap==Yp): each wave loads its 16 rows into regs before any store.
template<int TRANSFORM>
__launch_bounds__(256)
__global__ void gemm_mfma(const void* Ap, const float* __restrict__ Wp,
                          const float* __restrict__ bias,
                          const float* __restrict__ scale, const float* __restrict__ shift,
                          float* Yp, float* __restrict__ osum, float* __restrict__ osq) {
    __shared__ u16 sW[128 * 136];   // row stride 136 u16 = 272 B -> bank rotation, 2-way max (free)
    __shared__ float sScale[128], sShift[128], sBias[128], sSum[128], sSq[128];
    int t = threadIdx.x, lane = t & 63, wv = t >> 6;

    // stage W: 4096 float4 loads, convert to bf16
    #pragma unroll
    for (int it = 0; it < 16; it++) {
        int q = it * 256 + t;           // float4 index in [0,4096)
        int r = q >> 5, cq = q & 31;    // row, 4-col group
        floatx4 w = ((const floatx4*)Wp)[q];
        u16 b[4] = {f2bfbits(w[0]), f2bfbits(w[1]), f2bfbits(w[2]), f2bfbits(w[3])};
        *(uint2*)&sW[r * 136 + cq * 4] = *(uint2*)b;
    }
    if (t < 128) {
        sSum[t] = 0.f; sSq[t] = 0.f; sBias[t] = bias[t];
        if (TRANSFORM) { sScale[t] = scale[t]; sShift[t] = shift[t]; }
    }
    __syncthreads();

    int tile = blockIdx.x * 4 + wv;           // 16-row tile; 3125 tiles total
    if (tile < (N_NODES / 16)) {
        int col0 = lane & 15, quad = lane >> 4;
        int mrow = tile * 16 + col0;

        short8 afr[4];
        if (TRANSFORM == 0) {
            const u16* A = (const u16*)Ap;    // h, bf16
            #pragma unroll
            for (int ks = 0; ks < 4; ks++)
                afr[ks] = *(const short8*)&A[mrow * DIM + ks * 32 + quad * 8];
        } else {
            const float* A = (const float*)Ap;  // y, fp32
            #pragma unroll
            for (int ks = 0; ks < 4; ks++) {
                int kb = ks * 32 + quad * 8;
                floatx4 v0 = *(const floatx4*)&A[mrow * DIM + kb];
                floatx4 v1 = *(const floatx4*)&A[mrow * DIM + kb + 4];
                short8 r;
                #pragma unroll
                for (int j = 0; j < 4; j++) {
                    r[j]     = (short)f2bfbits(fmaxf(fmaf(v0[j], sScale[kb + j],     sShift[kb + j]),     0.f));
                    r[j + 4] = (short)f2bfbits(fmaxf(fmaf(v1[j], sScale[kb + 4 + j], sShift[kb + 4 + j]), 0.f));
                }
                afr[ks] = r;
            }
        }

        floatx4 acc[8];
        #pragma unroll
        for (int nt = 0; nt < 8; nt++) acc[nt] = (floatx4){0.f, 0.f, 0.f, 0.f};
        #pragma unroll
        for (int ks = 0; ks < 4; ks++) {
            #pragma unroll
            for (int nt = 0; nt < 8; nt++) {
                short8 bfr = *(const short8*)&sW[(nt * 16 + col0) * 136 + ks * 32 + quad * 8];
                acc[nt] = __builtin_amdgcn_mfma_f32_16x16x32_bf16(afr[ks], bfr, acc[nt], 0, 0, 0);
            }
        }

        // epilogue: bias, store (C/D: col=lane&15, row=quad*4+reg), fused stats
        #pragma unroll
        for (int nt = 0; nt < 8; nt++) {
            int col = nt * 16 + col0;
            float bb = sBias[col];
            float o0 = acc[nt][0] + bb, o1 = acc[nt][1] + bb;
            float o2 = acc[nt][2] + bb, o3 = acc[nt][3] + bb;
            int rbase = tile * 16 + quad * 4;
            Yp[(rbase + 0) * DIM + col] = o0;
            Yp[(rbase + 1) * DIM + col] = o1;
            Yp[(rbase + 2) * DIM + col] = o2;
            Yp[(rbase + 3) * DIM + col] = o3;
            float s = o0 + o1 + o2 + o3;
            float q = o0 * o0 + o1 * o1 + o2 * o2 + o3 * o3;
            s += __shfl_xor(s, 16); s += __shfl_xor(s, 32);
            q += __shfl_xor(q, 16); q += __shfl_xor(q, 32);
            if (quad == 0) { atomicAdd(&sSum[col], s); atomicAdd(&sSq[col], q); }
        }
    }
    __syncthreads();
    if (t < 128) { atomicAdd(&osum[t], sSum[t]); atomicAdd(&osq[t], sSq[t]); }
}

__global__ void finalize_kernel(const float* __restrict__ sum, const float* __restrict__ sumsq,
                                const float* __restrict__ gamma, const float* __restrict__ beta,
                                float* __restrict__ scale, float* __restrict__ shift) {
    int c = threadIdx.x;
    if (c < 128) {
        float m = sum[c] * (1.0f / N_NODES);
        float v = sumsq[c] * (1.0f / N_NODES) - m * m;
        v = fmaxf(v, 0.0f);
        float rs = rsqrtf(v + 1e-5f);
        float sc = gamma[c] * rs;
        scale[c] = sc;
        shift[c] = beta[c] - m * sc;
    }
}

// ---------------- final BN2 + ReLU, fp32 out (8 elems/thread) ----------------
__global__ void output_kernel(const float* __restrict__ Y, const float* __restrict__ scale,
                              const float* __restrict__ shift, float* __restrict__ out) {
    int i = (blockIdx.x * blockDim.x + threadIdx.x) * 8;
    if (i >= N_NODES * DIM) return;
    int c = i & 127;
    floatx4 v0 = *(const floatx4*)&Y[i];
    floatx4 v1 = *(const floatx4*)&Y[i + 4];
    floatx4 o0, o1;
    #pragma unroll
    for (int j = 0; j < 4; j++) {
        o0[j] = fmaxf(fmaf(v0[j], scale[c + j],     shift[c + j]),     0.f);
        o1[j] = fmaxf(fmaf(v1[j], scale[c + 4 + j], shift[c + 4 + j]), 0.f);
    }
    *(floatx4*)&out[i] = o0;
    *(floatx4*)&out[i + 4] = o1;
}

extern "C" void kernel_launch(void* const* d_in, const int* in_sizes, int n_in,
                              void* d_out, int out_size, void* d_ws, size_t ws_size,
                              hipStream_t stream) {
    const float2* x  = (const float2*)d_in[0];   // fp32
    const int* eraw  = (const int*)d_in[1];
    const float* eps = (const float*)d_in[3];
    const float* W1  = (const float*)d_in[4];
    const float* b1  = (const float*)d_in[5];
    const float* g1  = (const float*)d_in[6];
    const float* be1 = (const float*)d_in[7];
    const float* W2  = (const float*)d_in[8];
    const float* b2  = (const float*)d_in[9];
    const float* g2  = (const float*)d_in[10];
    const float* be2 = (const float*)d_in[11];

    char* ws = (char*)d_ws;
    size_t off = 0;
    unsigned* h = (unsigned*)(ws + off); off += (size_t)N_NODES * DIM * 2;   // bf16, 12.8 MB
    float* y = (float*)(ws + off);       off += (size_t)N_NODES * DIM * 4;   // fp32, 25.6 MB
    int* cnt = (int*)(ws + off);         off += (size_t)N_NODES * 4;         // zero-region start
    float* stats = (float*)(ws + off);   off += 4 * 128 * 4;                 // sum1,sq1,sum2,sq2 (zeroed with cnt)
    float* sum1 = stats, *sq1 = stats + 128, *sum2 = stats + 256, *sq2 = stats + 384;
    float* scale1 = (float*)(ws + off);  off += 128 * 4;
    float* shift1 = (float*)(ws + off);  off += 128 * 4;
    float* scale2 = (float*)(ws + off);  off += 128 * 4;
    float* shift2 = (float*)(ws + off);  off += 128 * 4;
    int* offsets = (int*)(ws + off);     off += (size_t)(N_NODES + 16) * 4;
    int* cursor = (int*)(ws + off);      off += (size_t)(N_NODES + 16) * 4;
    int* nbrs = (int*)(ws + off);        off += (size_t)N_EDGES * 4;
    int* bsums = (int*)(ws + off);       off += 64 * 4;
    int* boffs = (int*)(ws + off);       off += 64 * 4;
    int* flags = (int*)(ws + off);       off += 16 * 4;

    const int nbScan = (N_NODES + 1023) / 1024;  // 49

    detect_kernel<<<1, 64, 0, stream>>>(eraw, flags);

    int zn = N_NODES + 4 * 128;
    zero_kernel<<<(zn + 255) / 256, 256, 0, stream>>>(cnt, zn);
    hist_kernel<<<(N_EDGES + 255) / 256, 256, 0, stream>>>(eraw, flags, cnt);
    scan_part<<<nbScan, 256, 0, stream>>>(cnt, bsums);
    scan_tops<<<1, 64, 0, stream>>>(bsums, boffs, offsets, nbScan);
    scan_down<<<nbScan, 256, 0, stream>>>(cnt, boffs, offsets, cursor);
    fill_kernel<<<(N_EDGES + 255) / 256, 256, 0, stream>>>(eraw, flags, cursor, nbrs);
    agg_kernel<<<N_NODES / 4, 256, 0, stream>>>(x, offsets, nbrs, eps, h);

    const int gemmGrid = (N_NODES / 16 + 3) / 4;  // 782 blocks, 4 wave-tiles each
    gemm_mfma<0><<<gemmGrid, 256, 0, stream>>>(h, W1, b1, nullptr, nullptr, y, sum1, sq1);
    finalize_kernel<<<1, 128, 0, stream>>>(sum1, sq1, g1, be1, scale1, shift1);
    gemm_mfma<1><<<gemmGrid, 256, 0, stream>>>(y, W2, b2, scale1, shift1, y, sum2, sq2);
    finalize_kernel<<<1, 128, 0, stream>>>(sum2, sq2, g2, be2, scale2, shift2);
    output_kernel<<<(N_NODES * DIM / 8 + 255) / 256, 256, 0, stream>>>(y, scale2, shift2, (float*)d_out);
}